// Round 15
// baseline (213.807 us; speedup 1.0000x reference)
//
#include <hip/hip_runtime.h>
#include <hip/hip_bf16.h>

typedef __bf16 bf16;
typedef __bf16 bf16x8 __attribute__((ext_vector_type(8)));
typedef __bf16 bf16x4 __attribute__((ext_vector_type(4)));
typedef float f32x4 __attribute__((ext_vector_type(4)));
typedef float f32x16 __attribute__((ext_vector_type(16)));

#define MFMA16(a, b, c) __builtin_amdgcn_mfma_f32_16x16x32_bf16((a), (b), (c), 0, 0, 0)
#define MFMA32(a, b, c) __builtin_amdgcn_mfma_f32_32x32x16_bf16((a), (b), (c), 0, 0, 0)

constexpr int S = 4096;
constexpr int E = 1024;
constexpr int H = 16;
constexpr int HD = 64;
constexpr float NEG = -1e30f;
// scores in log2 domain: fold 1/sqrt(64) * log2(e) into Q
constexpr float QSCALE = 0.125f * 1.44269504088896f;

__device__ inline f32x16 fzero16() {
  f32x16 z;
#pragma unroll
  for (int i = 0; i < 16; ++i) z[i] = 0.f;
  return z;
}

__device__ inline bf16x8 load_f32x8_as_bf16(const float* __restrict__ p) {
  float4 u0 = *reinterpret_cast<const float4*>(p);
  float4 u1 = *reinterpret_cast<const float4*>(p + 4);
  bf16x8 r;
  r[0] = (bf16)u0.x; r[1] = (bf16)u0.y; r[2] = (bf16)u0.z; r[3] = (bf16)u0.w;
  r[4] = (bf16)u1.x; r[5] = (bf16)u1.y; r[6] = (bf16)u1.z; r[7] = (bf16)u1.w;
  return r;
}

// ---------------- QKV projection (+ wo->bf16 folded in as blockIdx.y == 16) ----------------
// Q pre-scaled by QSCALE; V written TRANSPOSED: vt[h][d][s]
__global__ __launch_bounds__(256) void qkv_cvt_kernel(
    const float* __restrict__ x, const float* __restrict__ wq,
    const float* __restrict__ wk, const float* __restrict__ wv,
    const float* __restrict__ wo,
    bf16* __restrict__ qb, bf16* __restrict__ kb, bf16* __restrict__ vt,
    bf16* __restrict__ wob) {
  if (blockIdx.y == 16) {  // wo -> bf16 conversion lane
    for (int i = (blockIdx.x * 256 + threadIdx.x) * 4; i < E * E; i += 64 * 256 * 4) {
      float4 f = *reinterpret_cast<const float4*>(wo + i);
      bf16x4 b;
      b[0] = (bf16)f.x; b[1] = (bf16)f.y; b[2] = (bf16)f.z; b[3] = (bf16)f.w;
      *reinterpret_cast<bf16x4*>(wob + i) = b;
    }
    return;
  }
  const int h = blockIdx.y;
  const int s0 = blockIdx.x * 64;
  const int w = threadIdx.x >> 6;
  const int l = threadIdx.x & 63;
  const int lg = l >> 4, lr = l & 15;

  bf16x8 af[2];
  {
    const float* xp = x + (size_t)(s0 + w * 16 + lr) * E + h * HD;
    af[0] = load_f32x8_as_bf16(xp + lg * 8);
    af[1] = load_f32x8_as_bf16(xp + 32 + lg * 8);
  }
  const float* Wsrc[3] = {wq + (size_t)h * HD * HD, wk + (size_t)h * HD * HD,
                          wv + (size_t)h * HD * HD};
#pragma unroll
  for (int pj = 0; pj < 3; ++pj) {
    f32x4 acc[4];
#pragma unroll
    for (int ot = 0; ot < 4; ++ot) acc[ot] = f32x4{0.f, 0.f, 0.f, 0.f};
#pragma unroll
    for (int ks = 0; ks < 2; ++ks) {
#pragma unroll
      for (int ot = 0; ot < 4; ++ot) {
        bf16x8 bfr = load_f32x8_as_bf16(Wsrc[pj] + (size_t)(ot * 16 + lr) * HD + ks * 32 + lg * 8);
        acc[ot] = MFMA16(af[ks], bfr, acc[ot]);
      }
    }
    if (pj == 2) {
      // V^T store: vt[(h*HD + o)][s]
#pragma unroll
      for (int ot = 0; ot < 4; ++ot) {
        bf16x4 b;
#pragma unroll
        for (int r = 0; r < 4; ++r) b[r] = (bf16)acc[ot][r];
        *reinterpret_cast<bf16x4*>(vt + (size_t)(h * HD + ot * 16 + lr) * S +
                                   s0 + w * 16 + lg * 4) = b;
      }
    } else {
      const float scale = (pj == 0) ? QSCALE : 1.0f;
      bf16* op = ((pj == 0) ? qb : kb) + (size_t)h * S * HD;
#pragma unroll
      for (int ot = 0; ot < 4; ++ot)
#pragma unroll
        for (int r = 0; r < 4; ++r)
          op[(size_t)(s0 + w * 16 + lg * 4 + r) * HD + ot * 16 + lr] =
              (bf16)(acc[ot][r] * scale);
    }
  }
}

// ---------------- causal flash attention: 8-wave kv-split, K-in-LDS (32 KB), V direct ----------------
// waves 0-3 (grp0) EVEN 64-kv tiles, waves 4-7 (grp1) ODD tiles of the same
// 128 q-rows. Only K is LDS-staged (dbuf 2x16KB = 32 KB total -> 2 blocks/CU
// co-residency guaranteed, proven at 32 KB in R10/R12). V loaded direct from
// global per wave (R5/R9-proven; coalesced via vt layout; issued under softmax).
// Skip guard prevents the masked-first-tile poison. Exact 2-phase merge through
// the K-LDS at the end. launch_bounds(512,2): no spill (R14: VGPR 72).
__global__ __launch_bounds__(512, 2) void attn_kernel(
    const bf16* __restrict__ qb, const bf16* __restrict__ kb,
    const bf16* __restrict__ vt, bf16* __restrict__ ob) {
  __shared__ bf16 Kl[2][2][4096];  // [buf][parity][row*64 + swizzled col] = 32 KB
  const int b = blockIdx.x;
  const int xcd = b & 7;
  const int idx = b >> 3;                    // 0..63
  const int p = idx >> 1, hb = idx & 1;
  const int head = 2 * xcd + hb;
  const int qt = (p < 16) ? (hb ? p : 31 - p) : (hb ? 47 - p : p - 16);
  const int tid = threadIdx.x;
  const int w = tid >> 6, l = tid & 63;
  const int w2 = w & 3, grp = w >> 2;        // grp0: even tiles, grp1: odd tiles
  const int lo = l & 31, hi = l >> 5;
  const int q0w = qt * 128 + w2 * 32;
  const int nss = qt + 1;                    // superstages (128 kv), block-uniform

  bf16x8 qf[4];
  {
    const bf16* qp = qb + ((size_t)head * S + q0w + lo) * HD + hi * 8;
#pragma unroll
    for (int dt = 0; dt < 4; ++dt) qf[dt] = *reinterpret_cast<const bf16x8*>(qp + dt * 16);
  }
  const bf16* kbase = kb + (size_t)head * S * HD;
  const bf16* vbase = vt + (size_t)head * HD * S;

  f32x16 acc0 = fzero16(), acc1 = fzero16();
  float mrun = NEG, lsum = 0.f;

  // K staging: 512 threads x 2 granules (16B); 128 kv rows per superstage
  auto gloadK = [&](int ss, bf16x8 (&kr)[2]) {
    const int kv0 = ss * 128;
#pragma unroll
    for (int j = 0; j < 2; ++j) {
      const int g = tid + j * 512;           // 0..1023
      const int krow = g >> 3, kge = g & 7;
      kr[j] = *reinterpret_cast<const bf16x8*>(kbase + (size_t)(kv0 + krow) * HD + kge * 8);
    }
  };
  auto swriteK = [&](int buf, bf16x8 (&kr)[2]) {
#pragma unroll
    for (int j = 0; j < 2; ++j) {
      const int g = tid + j * 512;
      const int krow = g >> 3, kge = g & 7;
      const int kpar = krow >> 6, kr6 = krow & 63;
      *reinterpret_cast<bf16x8*>(
          &Kl[buf][kpar][kr6 * 64 + ((kge * 8) ^ ((kr6 & 7) << 3))]) = kr[j];
    }
  };

  {
    bf16x8 kr[2];
    gloadK(0, kr);
    swriteK(0, kr);
  }
  __syncthreads();

  for (int ss = 0; ss < nss; ++ss) {
    const int buf = ss & 1;
    const bool pre = (ss + 1 < nss);
    const int kv0 = (2 * ss + grp) * 64;     // this wave's 64-kv tile

    if (kv0 <= q0w + 31) {  // skip fully-masked tiles (exact: contribution 0)
      // --- S^T[kv][q] = K @ Q from LDS (swizzled ds_read_b128) ---
      f32x16 sv[2];
      __builtin_amdgcn_s_setprio(1);
#pragma unroll
      for (int t = 0; t < 2; ++t) {
        f32x16 a = fzero16();
#pragma unroll
        for (int dt = 0; dt < 4; ++dt) {
          bf16x8 kf = *reinterpret_cast<const bf16x8*>(
              &Kl[buf][grp][(t * 32 + lo) * 64 + ((dt * 16 + hi * 8) ^ ((lo & 7) << 3))]);
          a = MFMA32(kf, qf[dt], a);
        }
        sv[t] = a;
      }
      __builtin_amdgcn_s_setprio(0);
      // --- V direct loads, issued early (hidden under mask+softmax VALU) ---
      bf16x8 vf[2][2][2];
#pragma unroll
      for (int t = 0; t < 2; ++t)
#pragma unroll
        for (int dh = 0; dh < 2; ++dh) {
          const bf16* vp = vbase + (size_t)(dh * 32 + lo) * S + kv0 + t * 32 + hi * 8;
          vf[t][dh][0] = *reinterpret_cast<const bf16x8*>(vp);
          vf[t][dh][1] = *reinterpret_cast<const bf16x8*>(vp + 16);
        }
      // --- causal mask (near-diagonal tiles only) ---
      if (kv0 + 63 > q0w) {
        const int q = q0w + lo;
#pragma unroll
        for (int t = 0; t < 2; ++t)
#pragma unroll
          for (int r = 0; r < 16; ++r) {
            int kv = kv0 + t * 32 + (r & 3) + 8 * (r >> 2) + 4 * hi;
            if (kv > q) sv[t][r] = NEG;
          }
      }
      // --- online softmax (log2 domain, defer-max thr=8) ---
      float tmax = NEG;
#pragma unroll
      for (int t = 0; t < 2; ++t)
#pragma unroll
        for (int r = 0; r < 16; ++r) tmax = fmaxf(tmax, sv[t][r]);
      if (!__all(tmax <= mrun + 8.f)) {
        float tm = fmaxf(tmax, __shfl_xor(tmax, 32));
        float mnew = fmaxf(mrun, tm);
        float alpha = exp2f(mrun - mnew);
        lsum *= alpha;
#pragma unroll
        for (int ii = 0; ii < 16; ++ii) { acc0[ii] *= alpha; acc1[ii] *= alpha; }
        mrun = mnew;
      }
      float psum = 0.f;
#pragma unroll
      for (int t = 0; t < 2; ++t)
#pragma unroll
        for (int r = 0; r < 16; ++r) {
          sv[t][r] = exp2f(sv[t][r] - mrun);
          psum += sv[t][r];
        }
      lsum += psum;
      // --- P -> bf16 pairs; half-wave exchange via permlane32_swap; PV (V in regs) ---
#pragma unroll
      for (int t = 0; t < 2; ++t) {
        unsigned wv[8];
#pragma unroll
        for (int ii = 0; ii < 8; ++ii) {
          union { unsigned u; bf16 h2[2]; } pu;
          pu.h2[0] = (bf16)sv[t][2 * ii];
          pu.h2[1] = (bf16)sv[t][2 * ii + 1];
          wv[ii] = pu.u;
        }
        asm("v_permlane32_swap_b32 %0, %1" : "+v"(wv[0]), "+v"(wv[2]));
        asm("v_permlane32_swap_b32 %0, %1" : "+v"(wv[1]), "+v"(wv[3]));
        asm("v_permlane32_swap_b32 %0, %1" : "+v"(wv[4]), "+v"(wv[6]));
        asm("v_permlane32_swap_b32 %0, %1" : "+v"(wv[5]), "+v"(wv[7]));
        union { bf16x8 v; unsigned u[4]; } B0, B1;
        B0.u[0] = wv[0]; B0.u[1] = wv[1]; B0.u[2] = wv[2]; B0.u[3] = wv[3];
        B1.u[0] = wv[4]; B1.u[1] = wv[5]; B1.u[2] = wv[6]; B1.u[3] = wv[7];
        __builtin_amdgcn_s_setprio(1);
        acc0 = MFMA32(vf[t][0][0], B0.v, acc0);
        acc0 = MFMA32(vf[t][0][1], B1.v, acc0);
        acc1 = MFMA32(vf[t][1][0], B0.v, acc1);
        acc1 = MFMA32(vf[t][1][1], B1.v, acc1);
        __builtin_amdgcn_s_setprio(0);
      }
    }
    // --- stage next superstage's K (tight liveness); lockstep barrier ---
    if (pre) {
      bf16x8 kr[2];
      gloadK(ss + 1, kr);
      swriteK(buf ^ 1, kr);
    }
    __syncthreads();
  }

  // --- exact 2-phase merge of grp1 into grp0 through the 32 KB K-LDS ---
  float* fK = (float*)Kl;                    // 8192 floats
  const int rowi = w2 * 64 + l;              // 0..255
  float sA = 0.f, sB = 0.f, inv = 0.f;
  // phase A: acc0 + m/l
  if (grp == 1) {
#pragma unroll
    for (int r = 0; r < 16; ++r) fK[rowi * 17 + r] = acc0[r];
    fK[4352 + rowi * 2] = mrun;
    fK[4352 + rowi * 2 + 1] = lsum;
  }
  __syncthreads();
  if (grp == 0) {
    const float mO = fK[4352 + rowi * 2];
    const float lO = fK[4352 + rowi * 2 + 1];
    const float M = fmaxf(mrun, mO);
    sA = exp2f(mrun - M);
    sB = exp2f(mO - M);
    float lc = lsum * sA + lO * sB;
#pragma unroll
    for (int r = 0; r < 16; ++r) acc0[r] = acc0[r] * sA + fK[rowi * 17 + r] * sB;
    inv = 1.0f / (lc + __shfl_xor(lc, 32));
  }
  __syncthreads();
  // phase B: acc1
  if (grp == 1) {
#pragma unroll
    for (int r = 0; r < 16; ++r) fK[rowi * 17 + r] = acc1[r];
  }
  __syncthreads();
  if (grp == 0) {
#pragma unroll
    for (int r = 0; r < 16; ++r) acc1[r] = acc1[r] * sA + fK[rowi * 17 + r] * sB;
    bf16* obp = ob + (size_t)(q0w + lo) * E + head * HD;
#pragma unroll
    for (int dh = 0; dh < 2; ++dh)
#pragma unroll
      for (int g = 0; g < 4; ++g) {
        bf16x4 bb;
#pragma unroll
        for (int r = 0; r < 4; ++r)
          bb[r] = (bf16)(((dh == 0) ? acc0[g * 4 + r] : acc1[g * 4 + r]) * inv);
        *reinterpret_cast<bf16x4*>(obp + dh * 32 + 8 * g + 4 * hi) = bb;
      }
  }
}

// ---------------- output projection: out = attn @ wo^T (128x64 tiles, R10-proven) ----------------
__global__ __launch_bounds__(256) void out_gemm_kernel(
    const bf16* __restrict__ ob, const bf16* __restrict__ wob,
    float* __restrict__ out) {
  const int w = threadIdx.x >> 6, l = threadIdx.x & 63, lg = l >> 4, lr = l & 15;
  const int s0 = blockIdx.x * 128, e0 = blockIdx.y * 64;
  f32x4 acc[2][4];
#pragma unroll
  for (int i = 0; i < 2; ++i)
#pragma unroll
    for (int jj = 0; jj < 4; ++jj) acc[i][jj] = f32x4{0.f, 0.f, 0.f, 0.f};
  const bf16* ap0 = ob + (size_t)(s0 + w * 16 + lr) * E;
  const bf16* ap1 = ap0 + (size_t)64 * E;
#pragma unroll 2
  for (int k = 0; k < E; k += 32) {
    bf16x8 a0 = *reinterpret_cast<const bf16x8*>(ap0 + k + lg * 8);
    bf16x8 a1 = *reinterpret_cast<const bf16x8*>(ap1 + k + lg * 8);
#pragma unroll
    for (int ct = 0; ct < 4; ++ct) {
      bf16x8 bfr = *reinterpret_cast<const bf16x8*>(
          wob + (size_t)(e0 + ct * 16 + lr) * E + k + lg * 8);
      acc[0][ct] = MFMA16(a0, bfr, acc[0][ct]);
      acc[1][ct] = MFMA16(a1, bfr, acc[1][ct]);
    }
  }
#pragma unroll
  for (int half = 0; half < 2; ++half)
#pragma unroll
    for (int ct = 0; ct < 4; ++ct)
#pragma unroll
      for (int r = 0; r < 4; ++r)
        out[(size_t)(s0 + half * 64 + w * 16 + lg * 4 + r) * E + e0 + ct * 16 + lr] =
            acc[half][ct][r];
}

extern "C" void kernel_launch(void* const* d_in, const int* in_sizes, int n_in,
                              void* d_out, int out_size, void* d_ws, size_t ws_size,
                              hipStream_t stream) {
  const float* x  = (const float*)d_in[0];
  const float* wq = (const float*)d_in[1];
  const float* wk = (const float*)d_in[2];
  const float* wv = (const float*)d_in[3];
  const float* wo = (const float*)d_in[4];
  float* out = (float*)d_out;

  bf16* qb  = (bf16*)d_ws;                 // [H][S][HD]
  bf16* kb  = qb + (size_t)H * S * HD;     // [H][S][HD]
  bf16* vt  = kb + (size_t)H * S * HD;     // [H][HD][S]  (V transposed)
  bf16* ob  = vt + (size_t)H * S * HD;     // [S][E]
  bf16* wob = ob + (size_t)S * E;          // [E][E]

  qkv_cvt_kernel<<<dim3(S / 64, H + 1), 256, 0, stream>>>(x, wq, wk, wv, wo, qb, kb, vt, wob);
  attn_kernel<<<dim3(512), 512, 0, stream>>>(qb, kb, vt, ob);
  out_gemm_kernel<<<dim3(S / 128, E / 64), 256, 0, stream>>>(ob, wob, out);
}

// Round 16
// 180.329 us; speedup vs baseline: 1.1857x; 1.1857x over previous
//
#include <hip/hip_runtime.h>
#include <hip/hip_bf16.h>

typedef __bf16 bf16;
typedef __bf16 bf16x8 __attribute__((ext_vector_type(8)));
typedef __bf16 bf16x4 __attribute__((ext_vector_type(4)));
typedef float f32x4 __attribute__((ext_vector_type(4)));
typedef float f32x16 __attribute__((ext_vector_type(16)));

#define MFMA16(a, b, c) __builtin_amdgcn_mfma_f32_16x16x32_bf16((a), (b), (c), 0, 0, 0)
#define MFMA32(a, b, c) __builtin_amdgcn_mfma_f32_32x32x16_bf16((a), (b), (c), 0, 0, 0)

constexpr int S = 4096;
constexpr int E = 1024;
constexpr int H = 16;
constexpr int HD = 64;
constexpr float NEG = -1e30f;
// scores in log2 domain: fold 1/sqrt(64) * log2(e) into Q
constexpr float QSCALE = 0.125f * 1.44269504088896f;

__device__ inline f32x16 fzero16() {
  f32x16 z;
#pragma unroll
  for (int i = 0; i < 16; ++i) z[i] = 0.f;
  return z;
}

__device__ inline bf16x8 load_f32x8_as_bf16(const float* __restrict__ p) {
  float4 u0 = *reinterpret_cast<const float4*>(p);
  float4 u1 = *reinterpret_cast<const float4*>(p + 4);
  bf16x8 r;
  r[0] = (bf16)u0.x; r[1] = (bf16)u0.y; r[2] = (bf16)u0.z; r[3] = (bf16)u0.w;
  r[4] = (bf16)u1.x; r[5] = (bf16)u1.y; r[6] = (bf16)u1.z; r[7] = (bf16)u1.w;
  return r;
}

// ---------------- QKV projection (+ wo->bf16 folded in as blockIdx.y == 16) ----------------
// Q pre-scaled by QSCALE; V written TRANSPOSED: vt[h][d][s]
__global__ __launch_bounds__(256) void qkv_cvt_kernel(
    const float* __restrict__ x, const float* __restrict__ wq,
    const float* __restrict__ wk, const float* __restrict__ wv,
    const float* __restrict__ wo,
    bf16* __restrict__ qb, bf16* __restrict__ kb, bf16* __restrict__ vt,
    bf16* __restrict__ wob) {
  if (blockIdx.y == 16) {  // wo -> bf16 conversion lane
    for (int i = (blockIdx.x * 256 + threadIdx.x) * 4; i < E * E; i += 64 * 256 * 4) {
      float4 f = *reinterpret_cast<const float4*>(wo + i);
      bf16x4 b;
      b[0] = (bf16)f.x; b[1] = (bf16)f.y; b[2] = (bf16)f.z; b[3] = (bf16)f.w;
      *reinterpret_cast<bf16x4*>(wob + i) = b;
    }
    return;
  }
  const int h = blockIdx.y;
  const int s0 = blockIdx.x * 64;
  const int w = threadIdx.x >> 6;
  const int l = threadIdx.x & 63;
  const int lg = l >> 4, lr = l & 15;

  bf16x8 af[2];
  {
    const float* xp = x + (size_t)(s0 + w * 16 + lr) * E + h * HD;
    af[0] = load_f32x8_as_bf16(xp + lg * 8);
    af[1] = load_f32x8_as_bf16(xp + 32 + lg * 8);
  }
  const float* Wsrc[3] = {wq + (size_t)h * HD * HD, wk + (size_t)h * HD * HD,
                          wv + (size_t)h * HD * HD};
#pragma unroll
  for (int pj = 0; pj < 3; ++pj) {
    f32x4 acc[4];
#pragma unroll
    for (int ot = 0; ot < 4; ++ot) acc[ot] = f32x4{0.f, 0.f, 0.f, 0.f};
#pragma unroll
    for (int ks = 0; ks < 2; ++ks) {
#pragma unroll
      for (int ot = 0; ot < 4; ++ot) {
        bf16x8 bfr = load_f32x8_as_bf16(Wsrc[pj] + (size_t)(ot * 16 + lr) * HD + ks * 32 + lg * 8);
        acc[ot] = MFMA16(af[ks], bfr, acc[ot]);
      }
    }
    if (pj == 2) {
      // V^T store: vt[(h*HD + o)][s]
#pragma unroll
      for (int ot = 0; ot < 4; ++ot) {
        bf16x4 b;
#pragma unroll
        for (int r = 0; r < 4; ++r) b[r] = (bf16)acc[ot][r];
        *reinterpret_cast<bf16x4*>(vt + (size_t)(h * HD + ot * 16 + lr) * S +
                                   s0 + w * 16 + lg * 4) = b;
      }
    } else {
      const float scale = (pj == 0) ? QSCALE : 1.0f;
      bf16* op = ((pj == 0) ? qb : kb) + (size_t)h * S * HD;
#pragma unroll
      for (int ot = 0; ot < 4; ++ot)
#pragma unroll
        for (int r = 0; r < 4; ++r)
          op[(size_t)(s0 + w * 16 + lg * 4 + r) * HD + ot * 16 + lr] =
              (bf16)(acc[ot][r] * scale);
    }
  }
}

// ---------------- causal flash attention: LDS-lockstep, XOR-swizzled K/V tiles ----------------
// (R12-verified, byte-identical.) 4 waves/block share K+V via 32 KB dbuf LDS;
// XCD b&7 serves heads {2x,2x+1}; qt map balanced under both CU-pairing models.
// Reg-staged async-split staging; XOR swizzle elem ^= (row&7)<<3 on write AND
// read; one barrier per stage; wave-uniform skip of fully-masked tiles.
__global__ __launch_bounds__(256, 2) void attn_kernel(
    const bf16* __restrict__ qb, const bf16* __restrict__ kb,
    const bf16* __restrict__ vt, bf16* __restrict__ ob) {
  __shared__ bf16 Kl[2][64 * 64];  // [buf][kv-row][d-col swizzled]
  __shared__ bf16 Vl[2][64 * 64];  // [buf][d-row][kv-col swizzled]
  const int b = blockIdx.x;
  const int xcd = b & 7;
  const int idx = b >> 3;                    // 0..63
  const int p = idx >> 1, hb = idx & 1;
  const int head = 2 * xcd + hb;
  const int qt = (p < 16) ? (hb ? p : 31 - p) : (hb ? 47 - p : p - 16);
  const int tid = threadIdx.x;
  const int w = tid >> 6, l = tid & 63;
  const int lo = l & 31, hi = l >> 5;
  const int q0w = qt * 128 + w * 32;
  const int nst = 2 * qt + 2;                // SAME for all waves (barrier-safe)

  bf16x8 qf[4];
  {
    const bf16* qp = qb + ((size_t)head * S + q0w + lo) * HD + hi * 8;
#pragma unroll
    for (int dt = 0; dt < 4; ++dt) qf[dt] = *reinterpret_cast<const bf16x8*>(qp + dt * 16);
  }
  const bf16* kbase = kb + (size_t)head * S * HD;
  const bf16* vbase = vt + (size_t)head * HD * S;

  f32x16 acc0 = fzero16(), acc1 = fzero16();
  float mrun = NEG, lsum = 0.f;

  // staging: 256 threads x 2 granules each for K and V (16B granules)
  auto gload = [&](int st, bf16x8 (&kr)[2], bf16x8 (&vr)[2]) {
    const int kv0 = st * 64;
#pragma unroll
    for (int j = 0; j < 2; ++j) {
      const int g = tid + j * 256;
      const int row = g >> 3, ge = g & 7;
      kr[j] = *reinterpret_cast<const bf16x8*>(kbase + (size_t)(kv0 + row) * HD + ge * 8);
      vr[j] = *reinterpret_cast<const bf16x8*>(vbase + (size_t)row * S + kv0 + ge * 8);
    }
  };
  auto swrite = [&](int buf, bf16x8 (&kr)[2], bf16x8 (&vr)[2]) {
#pragma unroll
    for (int j = 0; j < 2; ++j) {
      const int g = tid + j * 256;
      const int row = g >> 3, ge = g & 7;
      const int off = row * 64 + ((ge * 8) ^ ((row & 7) << 3));
      *reinterpret_cast<bf16x8*>(&Kl[buf][off]) = kr[j];
      *reinterpret_cast<bf16x8*>(&Vl[buf][off]) = vr[j];
    }
  };

  bf16x8 kr[2], vr[2];
  gload(0, kr, vr);
  swrite(0, kr, vr);
  __syncthreads();

  for (int st = 0; st < nst; ++st) {
    const int buf = st & 1;
    const int kv0 = st * 64;
    const bool pre = (st + 1 < nst);
    if (pre) gload(st + 1, kr, vr);  // issue early; consumed by swrite at stage end

    if (kv0 <= q0w + 31) {  // skip fully-masked tiles: contribution exactly 0
      // --- S^T[kv][q] = K @ Q from LDS (swizzled ds_read_b128) ---
      f32x16 sv[2];
      __builtin_amdgcn_s_setprio(1);
#pragma unroll
      for (int t = 0; t < 2; ++t) {
        f32x16 a = fzero16();
#pragma unroll
        for (int dt = 0; dt < 4; ++dt) {
          bf16x8 kf = *reinterpret_cast<const bf16x8*>(
              &Kl[buf][(t * 32 + lo) * 64 + ((dt * 16 + hi * 8) ^ ((lo & 7) << 3))]);
          a = MFMA32(kf, qf[dt], a);
        }
        sv[t] = a;
      }
      __builtin_amdgcn_s_setprio(0);
      // --- causal mask (near-diagonal stages only) ---
      if (kv0 + 63 > q0w) {
        const int q = q0w + lo;
#pragma unroll
        for (int t = 0; t < 2; ++t)
#pragma unroll
          for (int r = 0; r < 16; ++r) {
            int kv = kv0 + t * 32 + (r & 3) + 8 * (r >> 2) + 4 * hi;
            if (kv > q) sv[t][r] = NEG;
          }
      }
      // --- online softmax (log2 domain, defer-max thr=8) ---
      float tmax = NEG;
#pragma unroll
      for (int t = 0; t < 2; ++t)
#pragma unroll
        for (int r = 0; r < 16; ++r) tmax = fmaxf(tmax, sv[t][r]);
      if (!__all(tmax <= mrun + 8.f)) {
        float tm = fmaxf(tmax, __shfl_xor(tmax, 32));
        float mnew = fmaxf(mrun, tm);
        float alpha = exp2f(mrun - mnew);
        lsum *= alpha;
#pragma unroll
        for (int ii = 0; ii < 16; ++ii) { acc0[ii] *= alpha; acc1[ii] *= alpha; }
        mrun = mnew;
      }
      float psum = 0.f;
#pragma unroll
      for (int t = 0; t < 2; ++t)
#pragma unroll
        for (int r = 0; r < 16; ++r) {
          sv[t][r] = exp2f(sv[t][r] - mrun);
          psum += sv[t][r];
        }
      lsum += psum;
      // --- P -> bf16 pairs; half-wave exchange via permlane32_swap; PV from LDS ---
#pragma unroll
      for (int t = 0; t < 2; ++t) {
        unsigned wv[8];
#pragma unroll
        for (int ii = 0; ii < 8; ++ii) {
          union { unsigned u; bf16 h2[2]; } pu;
          pu.h2[0] = (bf16)sv[t][2 * ii];
          pu.h2[1] = (bf16)sv[t][2 * ii + 1];
          wv[ii] = pu.u;
        }
        asm("v_permlane32_swap_b32 %0, %1" : "+v"(wv[0]), "+v"(wv[2]));
        asm("v_permlane32_swap_b32 %0, %1" : "+v"(wv[1]), "+v"(wv[3]));
        asm("v_permlane32_swap_b32 %0, %1" : "+v"(wv[4]), "+v"(wv[6]));
        asm("v_permlane32_swap_b32 %0, %1" : "+v"(wv[5]), "+v"(wv[7]));
        union { bf16x8 v; unsigned u[4]; } B0, B1;
        B0.u[0] = wv[0]; B0.u[1] = wv[1]; B0.u[2] = wv[2]; B0.u[3] = wv[3];
        B1.u[0] = wv[4]; B1.u[1] = wv[5]; B1.u[2] = wv[6]; B1.u[3] = wv[7];
        __builtin_amdgcn_s_setprio(1);
#pragma unroll
        for (int dh = 0; dh < 2; ++dh) {
          bf16x8 v0 = *reinterpret_cast<const bf16x8*>(
              &Vl[buf][(dh * 32 + lo) * 64 + ((t * 32 + hi * 8) ^ ((lo & 7) << 3))]);
          bf16x8 v1 = *reinterpret_cast<const bf16x8*>(
              &Vl[buf][(dh * 32 + lo) * 64 + ((t * 32 + 16 + hi * 8) ^ ((lo & 7) << 3))]);
          if (dh == 0) { acc0 = MFMA32(v0, B0.v, acc0); acc0 = MFMA32(v1, B1.v, acc0); }
          else         { acc1 = MFMA32(v0, B0.v, acc1); acc1 = MFMA32(v1, B1.v, acc1); }
        }
        __builtin_amdgcn_s_setprio(0);
      }
    }
    // --- write next stage's tiles into the other buffer; lockstep barrier ---
    if (pre) swrite(buf ^ 1, kr, vr);
    __syncthreads();
  }

  const float inv = 1.0f / (lsum + __shfl_xor(lsum, 32));
  bf16* obp = ob + (size_t)(q0w + lo) * E + head * HD;
#pragma unroll
  for (int dh = 0; dh < 2; ++dh)
#pragma unroll
    for (int g = 0; g < 4; ++g) {
      bf16x4 bb;
#pragma unroll
      for (int r = 0; r < 4; ++r)
        bb[r] = (bf16)(((dh == 0) ? acc0[g * 4 + r] : acc1[g * 4 + r]) * inv);
      *reinterpret_cast<bf16x4*>(obp + dh * 32 + 8 * g + 4 * hi) = bb;
    }
}

// ---------------- output projection: out = attn @ wo^T (128x64 tiles, R10/R13-proven) ----------------
__global__ __launch_bounds__(256) void out_gemm_kernel(
    const bf16* __restrict__ ob, const bf16* __restrict__ wob,
    float* __restrict__ out) {
  const int w = threadIdx.x >> 6, l = threadIdx.x & 63, lg = l >> 4, lr = l & 15;
  const int s0 = blockIdx.x * 128, e0 = blockIdx.y * 64;
  f32x4 acc[2][4];
#pragma unroll
  for (int i = 0; i < 2; ++i)
#pragma unroll
    for (int jj = 0; jj < 4; ++jj) acc[i][jj] = f32x4{0.f, 0.f, 0.f, 0.f};
  const bf16* ap0 = ob + (size_t)(s0 + w * 16 + lr) * E;
  const bf16* ap1 = ap0 + (size_t)64 * E;
#pragma unroll 2
  for (int k = 0; k < E; k += 32) {
    bf16x8 a0 = *reinterpret_cast<const bf16x8*>(ap0 + k + lg * 8);
    bf16x8 a1 = *reinterpret_cast<const bf16x8*>(ap1 + k + lg * 8);
#pragma unroll
    for (int ct = 0; ct < 4; ++ct) {
      bf16x8 bfr = *reinterpret_cast<const bf16x8*>(
          wob + (size_t)(e0 + ct * 16 + lr) * E + k + lg * 8);
      acc[0][ct] = MFMA16(a0, bfr, acc[0][ct]);
      acc[1][ct] = MFMA16(a1, bfr, acc[1][ct]);
    }
  }
#pragma unroll
  for (int half = 0; half < 2; ++half)
#pragma unroll
    for (int ct = 0; ct < 4; ++ct)
#pragma unroll
      for (int r = 0; r < 4; ++r)
        out[(size_t)(s0 + half * 64 + w * 16 + lg * 4 + r) * E + e0 + ct * 16 + lr] =
            acc[half][ct][r];
}

extern "C" void kernel_launch(void* const* d_in, const int* in_sizes, int n_in,
                              void* d_out, int out_size, void* d_ws, size_t ws_size,
                              hipStream_t stream) {
  const float* x  = (const float*)d_in[0];
  const float* wq = (const float*)d_in[1];
  const float* wk = (const float*)d_in[2];
  const float* wv = (const float*)d_in[3];
  const float* wo = (const float*)d_in[4];
  float* out = (float*)d_out;

  bf16* qb  = (bf16*)d_ws;                 // [H][S][HD]
  bf16* kb  = qb + (size_t)H * S * HD;     // [H][S][HD]
  bf16* vt  = kb + (size_t)H * S * HD;     // [H][HD][S]  (V transposed)
  bf16* ob  = vt + (size_t)H * S * HD;     // [S][E]
  bf16* wob = ob + (size_t)S * E;          // [E][E]

  qkv_cvt_kernel<<<dim3(S / 64, H + 1), 256, 0, stream>>>(x, wq, wk, wv, wo, qb, kb, vt, wob);
  attn_kernel<<<dim3(512), 256, 0, stream>>>(qb, kb, vt, ob);
  out_gemm_kernel<<<dim3(S / 128, E / 64), 256, 0, stream>>>(ob, wob, out);
}

// Round 17
// 172.330 us; speedup vs baseline: 1.2407x; 1.0464x over previous
//
#include <hip/hip_runtime.h>
#include <hip/hip_bf16.h>

typedef __bf16 bf16;
typedef __bf16 bf16x8 __attribute__((ext_vector_type(8)));
typedef __bf16 bf16x4 __attribute__((ext_vector_type(4)));
typedef float f32x4 __attribute__((ext_vector_type(4)));

#define MFMA16(a, b, c) __builtin_amdgcn_mfma_f32_16x16x32_bf16((a), (b), (c), 0, 0, 0)

constexpr int S = 4096;
constexpr int E = 1024;
constexpr int H = 16;
constexpr int HD = 64;
constexpr float NEG = -1e30f;
// scores in log2 domain: fold 1/sqrt(64) * log2(e) into Q
constexpr float QSCALE = 0.125f * 1.44269504088896f;

__device__ inline bf16x8 load_f32x8_as_bf16(const float* __restrict__ p) {
  float4 u0 = *reinterpret_cast<const float4*>(p);
  float4 u1 = *reinterpret_cast<const float4*>(p + 4);
  bf16x8 r;
  r[0] = (bf16)u0.x; r[1] = (bf16)u0.y; r[2] = (bf16)u0.z; r[3] = (bf16)u0.w;
  r[4] = (bf16)u1.x; r[5] = (bf16)u1.y; r[6] = (bf16)u1.z; r[7] = (bf16)u1.w;
  return r;
}

// ---------------- QKV projection (+ wo->bf16 folded in as blockIdx.y == 16) ----------------
// Q pre-scaled by QSCALE; V written TRANSPOSED: vt[h][d][s]
__global__ __launch_bounds__(256) void qkv_cvt_kernel(
    const float* __restrict__ x, const float* __restrict__ wq,
    const float* __restrict__ wk, const float* __restrict__ wv,
    const float* __restrict__ wo,
    bf16* __restrict__ qb, bf16* __restrict__ kb, bf16* __restrict__ vt,
    bf16* __restrict__ wob) {
  if (blockIdx.y == 16) {  // wo -> bf16 conversion lane
    for (int i = (blockIdx.x * 256 + threadIdx.x) * 4; i < E * E; i += 64 * 256 * 4) {
      float4 f = *reinterpret_cast<const float4*>(wo + i);
      bf16x4 b;
      b[0] = (bf16)f.x; b[1] = (bf16)f.y; b[2] = (bf16)f.z; b[3] = (bf16)f.w;
      *reinterpret_cast<bf16x4*>(wob + i) = b;
    }
    return;
  }
  const int h = blockIdx.y;
  const int s0 = blockIdx.x * 64;
  const int w = threadIdx.x >> 6;
  const int l = threadIdx.x & 63;
  const int lg = l >> 4, lr = l & 15;

  bf16x8 af[2];
  {
    const float* xp = x + (size_t)(s0 + w * 16 + lr) * E + h * HD;
    af[0] = load_f32x8_as_bf16(xp + lg * 8);
    af[1] = load_f32x8_as_bf16(xp + 32 + lg * 8);
  }
  const float* Wsrc[3] = {wq + (size_t)h * HD * HD, wk + (size_t)h * HD * HD,
                          wv + (size_t)h * HD * HD};
#pragma unroll
  for (int pj = 0; pj < 3; ++pj) {
    f32x4 acc[4];
#pragma unroll
    for (int ot = 0; ot < 4; ++ot) acc[ot] = f32x4{0.f, 0.f, 0.f, 0.f};
#pragma unroll
    for (int ks = 0; ks < 2; ++ks) {
#pragma unroll
      for (int ot = 0; ot < 4; ++ot) {
        bf16x8 bfr = load_f32x8_as_bf16(Wsrc[pj] + (size_t)(ot * 16 + lr) * HD + ks * 32 + lg * 8);
        acc[ot] = MFMA16(af[ks], bfr, acc[ot]);
      }
    }
    if (pj == 2) {
      // V^T store: vt[(h*HD + o)][s]
#pragma unroll
      for (int ot = 0; ot < 4; ++ot) {
        bf16x4 b;
#pragma unroll
        for (int r = 0; r < 4; ++r) b[r] = (bf16)acc[ot][r];
        *reinterpret_cast<bf16x4*>(vt + (size_t)(h * HD + ot * 16 + lr) * S +
                                   s0 + w * 16 + lg * 4) = b;
      }
    } else {
      const float scale = (pj == 0) ? QSCALE : 1.0f;
      bf16* op = ((pj == 0) ? qb : kb) + (size_t)h * S * HD;
#pragma unroll
      for (int ot = 0; ot < 4; ++ot)
#pragma unroll
        for (int r = 0; r < 4; ++r)
          op[(size_t)(s0 + w * 16 + lg * 4 + r) * HD + ot * 16 + lr] =
              (bf16)(acc[ot][r] * scale);
    }
  }
}

// ---------------- causal flash attention: MFMA16, 4 waves x 16 q-cols, 4 blocks/CU ----------------
// Wave tile = 16 q-cols (16x16x32 MFMA) -> 4096 waves total = 4 waves/SIMD with
// no kv duplication. Same LDS-lockstep skeleton as R16: K/V staged once per
// block into 32 KB dbuf LDS, XOR swizzle on write+read, 1 barrier/stage.
// Swapped QK^T: S^T[kv][q] = mfma16(K-frag, Q-frag); P exchanged to PV B-frags
// with 16 __shfl + 8 selects per 64 kv (derivation verified element-wise).
// Grid 1024 = 8 XCDs x 2 heads x 64 q-tiles; qt pairs sum to 63 under both
// CU-pairing models.
__global__ __launch_bounds__(256, 4) void attn_kernel(
    const bf16* __restrict__ qb, const bf16* __restrict__ kb,
    const bf16* __restrict__ vt, bf16* __restrict__ ob) {
  __shared__ bf16 Kl[2][64 * 64];  // [buf][kv-row][d-col swizzled]
  __shared__ bf16 Vl[2][64 * 64];  // [buf][d-row][kv-col swizzled]
  const int b = blockIdx.x;
  const int xcd = b & 7;
  const int idx = b >> 3;                    // 0..127
  const int p = idx >> 1, hb = idx & 1;
  const int head = 2 * xcd + hb;
  const int qt = (p < 32) ? (hb ? p : 63 - p) : (hb ? 95 - p : p - 32);
  const int tid = threadIdx.x;
  const int w = tid >> 6, l = tid & 63;
  const int qc = l & 15, h = l >> 4;         // q-col within tile, lane group
  const int q0w = qt * 64 + w * 16;
  const int nst = qt + 1;                    // 64-kv stages, block-uniform

  bf16x8 qf[2];  // B-frag: col q = q0w+qc, k(d) = c*32 + h*8 + i
  {
    const bf16* qp = qb + ((size_t)head * S + q0w + qc) * HD + h * 8;
    qf[0] = *reinterpret_cast<const bf16x8*>(qp);
    qf[1] = *reinterpret_cast<const bf16x8*>(qp + 32);
  }
  const bf16* kbase = kb + (size_t)head * S * HD;
  const bf16* vbase = vt + (size_t)head * HD * S;

  f32x4 acc[4];  // O^T: col q = qc, row d = 16*dt + 4*h + r
#pragma unroll
  for (int i = 0; i < 4; ++i) acc[i] = f32x4{0.f, 0.f, 0.f, 0.f};
  float mrun = NEG, lsum = 0.f;

  // staging: 256 threads x 2 granules each for K and V (16B granules)
  auto gload = [&](int st, bf16x8 (&kr)[2], bf16x8 (&vr)[2]) {
    const int kv0 = st * 64;
#pragma unroll
    for (int j = 0; j < 2; ++j) {
      const int g = tid + j * 256;
      const int row = g >> 3, ge = g & 7;
      kr[j] = *reinterpret_cast<const bf16x8*>(kbase + (size_t)(kv0 + row) * HD + ge * 8);
      vr[j] = *reinterpret_cast<const bf16x8*>(vbase + (size_t)row * S + kv0 + ge * 8);
    }
  };
  auto swrite = [&](int buf, bf16x8 (&kr)[2], bf16x8 (&vr)[2]) {
#pragma unroll
    for (int j = 0; j < 2; ++j) {
      const int g = tid + j * 256;
      const int row = g >> 3, ge = g & 7;
      const int off = row * 64 + ((ge * 8) ^ ((row & 7) << 3));
      *reinterpret_cast<bf16x8*>(&Kl[buf][off]) = kr[j];
      *reinterpret_cast<bf16x8*>(&Vl[buf][off]) = vr[j];
    }
  };

  bf16x8 kr[2], vr[2];
  gload(0, kr, vr);
  swrite(0, kr, vr);
  __syncthreads();

  const int idxLo = ((2 * h) & 3) * 16 + qc;
  const int idxHi = ((2 * h + 1) & 3) * 16 + qc;

  for (int st = 0; st < nst; ++st) {
    const int buf = st & 1;
    const int kv0 = st * 64;
    const bool pre = (st + 1 < nst);
    if (pre) gload(st + 1, kr, vr);  // issue early; consumed by swrite at stage end

    if (kv0 <= q0w + 15) {  // skip fully-masked tiles (safety; exact)
      // --- S^T[kv][q] = K @ Q from LDS: A-frag row kv=16t+qc, k(d)=c*32+h*8 ---
      f32x4 sv[4];
#pragma unroll
      for (int t = 0; t < 4; ++t) sv[t] = f32x4{0.f, 0.f, 0.f, 0.f};
      __builtin_amdgcn_s_setprio(1);
#pragma unroll
      for (int c = 0; c < 2; ++c)
#pragma unroll
        for (int t = 0; t < 4; ++t) {
          bf16x8 kf = *reinterpret_cast<const bf16x8*>(
              &Kl[buf][(16 * t + qc) * 64 + ((c * 32 + h * 8) ^ ((qc & 7) << 3))]);
          sv[t] = MFMA16(kf, qf[c], sv[t]);
        }
      __builtin_amdgcn_s_setprio(0);
      // --- causal mask: lane holds kv = kv0+16t+4h+r, q = q0w+qc ---
      if (kv0 + 63 > q0w) {
        const int q = q0w + qc;
#pragma unroll
        for (int t = 0; t < 4; ++t)
#pragma unroll
          for (int r = 0; r < 4; ++r)
            if (kv0 + 16 * t + 4 * h + r > q) sv[t][r] = NEG;
      }
      // --- online softmax (log2 domain, defer-max thr=8) ---
      float tmax = NEG;
#pragma unroll
      for (int t = 0; t < 4; ++t)
#pragma unroll
        for (int r = 0; r < 4; ++r) tmax = fmaxf(tmax, sv[t][r]);
      if (!__all(tmax <= mrun + 8.f)) {
        float tm = fmaxf(tmax, __shfl_xor(tmax, 16));
        tm = fmaxf(tm, __shfl_xor(tm, 32));
        float mnew = fmaxf(mrun, tm);
        float alpha = exp2f(mrun - mnew);
        lsum *= alpha;
#pragma unroll
        for (int dt = 0; dt < 4; ++dt)
#pragma unroll
          for (int r = 0; r < 4; ++r) acc[dt][r] *= alpha;
        mrun = mnew;
      }
      float psum = 0.f;
#pragma unroll
      for (int t = 0; t < 4; ++t)
#pragma unroll
        for (int r = 0; r < 4; ++r) {
          sv[t][r] = exp2f(sv[t][r] - mrun);
          psum += sv[t][r];
        }
      lsum += psum;
      // --- P -> bf16 pairs per subtile ---
      unsigned pk[4][2];
#pragma unroll
      for (int t = 0; t < 4; ++t) {
        union { unsigned u; bf16 h2[2]; } a, bqq;
        a.h2[0] = (bf16)sv[t][0]; a.h2[1] = (bf16)sv[t][1];
        bqq.h2[0] = (bf16)sv[t][2]; bqq.h2[1] = (bf16)sv[t][3];
        pk[t][0] = a.u; pk[t][1] = bqq.u;
      }
      // --- PV: per 32-kv chunk c2, assemble B-frag via shfl (rows 8h..8h+7, col qc) ---
#pragma unroll
      for (int c2 = 0; c2 < 2; ++c2) {
        const int tA = 2 * c2, tB = 2 * c2 + 1;
        unsigned s00 = (unsigned)__shfl((int)pk[tA][0], idxLo);
        unsigned s01 = (unsigned)__shfl((int)pk[tA][1], idxLo);
        unsigned s02 = (unsigned)__shfl((int)pk[tA][0], idxHi);
        unsigned s03 = (unsigned)__shfl((int)pk[tA][1], idxHi);
        unsigned s10 = (unsigned)__shfl((int)pk[tB][0], idxLo);
        unsigned s11 = (unsigned)__shfl((int)pk[tB][1], idxLo);
        unsigned s12 = (unsigned)__shfl((int)pk[tB][0], idxHi);
        unsigned s13 = (unsigned)__shfl((int)pk[tB][1], idxHi);
        const bool lo2 = (h < 2);
        union { bf16x8 v; unsigned u[4]; } B;
        B.u[0] = lo2 ? s00 : s10;
        B.u[1] = lo2 ? s01 : s11;
        B.u[2] = lo2 ? s02 : s12;
        B.u[3] = lo2 ? s03 : s13;
        __builtin_amdgcn_s_setprio(1);
#pragma unroll
        for (int dt = 0; dt < 4; ++dt) {
          bf16x8 vf = *reinterpret_cast<const bf16x8*>(
              &Vl[buf][(16 * dt + qc) * 64 + ((c2 * 32 + h * 8) ^ ((qc & 7) << 3))]);
          acc[dt] = MFMA16(vf, B.v, acc[dt]);
        }
        __builtin_amdgcn_s_setprio(0);
      }
    }
    // --- write next stage's tiles into the other buffer; lockstep barrier ---
    if (pre) swrite(buf ^ 1, kr, vr);
    __syncthreads();
  }

  float lt = lsum + __shfl_xor(lsum, 16);
  lt += __shfl_xor(lt, 32);
  const float inv = 1.0f / lt;
  bf16* obp = ob + (size_t)(q0w + qc) * E + head * HD;
#pragma unroll
  for (int dt = 0; dt < 4; ++dt) {
    bf16x4 bb;
#pragma unroll
    for (int r = 0; r < 4; ++r) bb[r] = (bf16)(acc[dt][r] * inv);
    *reinterpret_cast<bf16x4*>(obp + 16 * dt + 4 * h) = bb;
  }
}

// ---------------- output projection: out = attn @ wo^T (128x64 tiles, R10/R13-proven) ----------------
__global__ __launch_bounds__(256) void out_gemm_kernel(
    const bf16* __restrict__ ob, const bf16* __restrict__ wob,
    float* __restrict__ out) {
  const int w = threadIdx.x >> 6, l = threadIdx.x & 63, lg = l >> 4, lr = l & 15;
  const int s0 = blockIdx.x * 128, e0 = blockIdx.y * 64;
  f32x4 acc[2][4];
#pragma unroll
  for (int i = 0; i < 2; ++i)
#pragma unroll
    for (int jj = 0; jj < 4; ++jj) acc[i][jj] = f32x4{0.f, 0.f, 0.f, 0.f};
  const bf16* ap0 = ob + (size_t)(s0 + w * 16 + lr) * E;
  const bf16* ap1 = ap0 + (size_t)64 * E;
#pragma unroll 2
  for (int k = 0; k < E; k += 32) {
    bf16x8 a0 = *reinterpret_cast<const bf16x8*>(ap0 + k + lg * 8);
    bf16x8 a1 = *reinterpret_cast<const bf16x8*>(ap1 + k + lg * 8);
#pragma unroll
    for (int ct = 0; ct < 4; ++ct) {
      bf16x8 bfr = *reinterpret_cast<const bf16x8*>(
          wob + (size_t)(e0 + ct * 16 + lr) * E + k + lg * 8);
      acc[0][ct] = MFMA16(a0, bfr, acc[0][ct]);
      acc[1][ct] = MFMA16(a1, bfr, acc[1][ct]);
    }
  }
#pragma unroll
  for (int half = 0; half < 2; ++half)
#pragma unroll
    for (int ct = 0; ct < 4; ++ct)
#pragma unroll
      for (int r = 0; r < 4; ++r)
        out[(size_t)(s0 + half * 64 + w * 16 + lg * 4 + r) * E + e0 + ct * 16 + lr] =
            acc[half][ct][r];
}

extern "C" void kernel_launch(void* const* d_in, const int* in_sizes, int n_in,
                              void* d_out, int out_size, void* d_ws, size_t ws_size,
                              hipStream_t stream) {
  const float* x  = (const float*)d_in[0];
  const float* wq = (const float*)d_in[1];
  const float* wk = (const float*)d_in[2];
  const float* wv = (const float*)d_in[3];
  const float* wo = (const float*)d_in[4];
  float* out = (float*)d_out;

  bf16* qb  = (bf16*)d_ws;                 // [H][S][HD]
  bf16* kb  = qb + (size_t)H * S * HD;     // [H][S][HD]
  bf16* vt  = kb + (size_t)H * S * HD;     // [H][HD][S]  (V transposed)
  bf16* ob  = vt + (size_t)H * S * HD;     // [S][E]
  bf16* wob = ob + (size_t)S * E;          // [E][E]

  qkv_cvt_kernel<<<dim3(S / 64, H + 1), 256, 0, stream>>>(x, wq, wk, wv, wo, qb, kb, vt, wob);
  attn_kernel<<<dim3(1024), 256, 0, stream>>>(qb, kb, vt, ob);
  out_gemm_kernel<<<dim3(S / 128, E / 64), 256, 0, stream>>>(ob, wob, out);
}